// Round 5
// baseline (87.537 us; speedup 1.0000x reference)
//
#include <hip/hip_runtime.h>
#include <math.h>

// Problem dims (fixed by setup_inputs)
#define N_  8
#define C_  4
#define A_  180
#define R_  180
#define NC  (N_*C_)        // 32
#define AR  (A_*R_)        // 32400
#define CAP 2048           // max peaks per (n,c) — expected ~450
#define RG  16             // rows per raster block
#define SL  16             // peak slices (threads per row)

typedef unsigned long long u64;
typedef unsigned int u32;

// ws layout (bytes) — zeroed prefix = [0, OFF_TBL)
#define OFF_MAXV 0                       // u32 maxv[32] (encoded float keys)
#define OFF_CNT  128                     // u32 cnt[32*32] (one line per nc)
#define OFF_TBL  4224                    // float ct[180] st[180] rp[180] (2176 B)
#define OFF_LIST 6400                    // u32 list[32][CAP] (256 KB)
#define ZERO_BYTES OFF_TBL

// monotone float <-> u32 key (for atomicMax on possibly-negative floats)
// note: memset-0 init is below every valid key (fkey(x) > 0 for all finite x)
__device__ __forceinline__ u32 fkey(float f) {
  u32 b = __float_as_uint(f);
  return (b & 0x80000000u) ? ~b : (b | 0x80000000u);
}
__device__ __forceinline__ float fval(u32 k) {
  u32 b = (k & 0x80000000u) ? (k ^ 0x80000000u) : ~k;
  return __uint_as_float(b);
}

// ---------------------------------------------------------------------------
// Kernel A: per-(n,c) max via 8 partial blocks + atomicMax (no return);
// block (8,0) builds trig/rho tables.
// ---------------------------------------------------------------------------
__global__ __launch_bounds__(256) void maxtbl_kernel(
    const float* __restrict__ hm,
    const int* __restrict__ Hp, const int* __restrict__ Wp,
    u32* __restrict__ maxv, float* __restrict__ tbl) {
  int bx = blockIdx.x, nc = blockIdx.y;
  if (bx < 8) {
    const float4* p = (const float4*)(hm + (size_t)nc * AR);  // 8100 float4
    float m = -INFINITY;
    for (int i = bx * 256 + threadIdx.x; i < AR / 4; i += 8 * 256) {
      float4 v = p[i];
      m = fmaxf(fmaxf(m, fmaxf(v.x, v.y)), fmaxf(v.z, v.w));
    }
    for (int off = 32; off; off >>= 1) m = fmaxf(m, __shfl_down(m, off, 64));
    __shared__ float sm[4];
    if ((threadIdx.x & 63) == 0) sm[threadIdx.x >> 6] = m;
    __syncthreads();
    if (threadIdx.x == 0) {
      m = fmaxf(fmaxf(sm[0], sm[1]), fmaxf(sm[2], sm[3]));
      atomicMax(&maxv[nc], fkey(m));
    }
  } else if (nc == 0) {
    int t = threadIdx.x;
    int H = Hp[0], W = Wp[0];
    double max_rho = sqrt((double)(W/2)*(double)(W/2) + (double)(H/2)*(double)(H/2));
    float drho = (float)(2.0 * max_rho / (double)(R_ - 1));
    if (t < A_) {
      // theta = f32(a) * f32(pi/A)  — matches jnp.arange(A,f32)*(np.pi/A)
      float theta = __fmul_rn((float)t, (float)(3.14159265358979323846 / (double)A_));
      tbl[t]        = (float)cos((double)theta);   // correctly-rounded f32
      tbl[A_ + t]   = (float)sin((double)theta);
      // r_phys = (f32(r) - 89.5) * f32(delta_rho)
      tbl[2*A_ + t] = __fmul_rn(__fsub_rn((float)t, (float)((R_-1)*0.5)), drho);
    }
  }
}

// ---------------------------------------------------------------------------
// Kernel B: peak detect -> compact list; ONE atomicAdd per wave (aggregated),
// counters padded one per 128-B line. Grid (127, 32): a wave never straddles nc.
// peak := hm > 0.5*max AND no 3x3 neighbor strictly greater (== maxpool SAME)
// ---------------------------------------------------------------------------
__global__ __launch_bounds__(256) void peaks_kernel(
    const float* __restrict__ hm, const u32* __restrict__ maxv,
    u32* __restrict__ cnt, u32* __restrict__ list) {
  int nc  = blockIdx.y;
  int idx = blockIdx.x * 256 + threadIdx.x;   // index within nc
  bool peak = false;
  int a = 0, r = 0;
  if (idx < AR) {
    const float* base = hm + (size_t)nc * AR;
    float val = base[idx];
    float thr = 0.5f * fval(maxv[nc]);
    if (val > thr) {
      a = idx / R_; r = idx - a * R_;
      peak = true;
      for (int da = -1; da <= 1 && peak; ++da) {
        int aa = a + da;
        if (aa < 0 || aa >= A_) continue;     // SAME pad with -inf
        for (int dr = -1; dr <= 1; ++dr) {
          if (da == 0 && dr == 0) continue;
          int rr = r + dr;
          if (rr < 0 || rr >= R_) continue;
          if (base[aa * R_ + rr] > val) { peak = false; break; }
        }
      }
    }
  }
  u64 m = __ballot(peak);
  if (m) {
    int lane = threadIdx.x & 63;
    int leader = (int)__ffsll((long long)m) - 1;
    u32 base_slot = 0;
    if (lane == leader) base_slot = atomicAdd(&cnt[nc * 32], (u32)__popcll(m));
    base_slot = (u32)__shfl((int)base_slot, leader, 64);
    if (peak) {
      u32 slot = base_slot + (u32)__popcll(m & ((1ull << lane) - 1ull));
      if (slot < CAP) list[(size_t)nc * CAP + slot] = (u32)((a << 8) | r);
    }
  }
}

// ---------------------------------------------------------------------------
// Kernel C (fused raster + writeout): block = (16-row stripe, nc); 256 thr =
// 16 rows x 16 peak slices. For fixed (peak,row), d(x) = f32(f32(xcv*ct)+yst)
// - rp is monotone in x (f32 rounding is monotone), so {x : |d|<mw} is one
// interval; two binary searches (s starts at 256 so u=256 "empty" answer is
// reachable) with the EXACT f32 predicate. Bits accumulate in private VGPRs,
// merge via LDS atomicOr (no global atomics -> no HBM write-through), block
// writes its disjoint 16x256 float tile directly with float4 stores.
// ---------------------------------------------------------------------------
__global__ __launch_bounds__(256) void raster_kernel(
    const float* __restrict__ mwp,
    const u32* __restrict__ cntg, const u32* __restrict__ listg,
    const float* __restrict__ tbl,
    float* __restrict__ out) {
  __shared__ u64 rowbits[RG][4];            // 512 B
  __shared__ float sct[CAP], sst[CAP], srp[CAP];  // 24 KB
  int yb  = blockIdx.x;                     // row stripe 0..15
  int nc  = blockIdx.y;
  int tid = threadIdx.x;
  int row = tid >> 4;                       // 0..15 local row
  int sub = tid & (SL - 1);                 // peak slice 0..15

  int cnt = (int)cntg[nc * 32]; if (cnt > CAP) cnt = CAP;

  for (int i = tid; i < cnt; i += 256) {
    u32 pk = listg[(size_t)nc * CAP + i];
    int a = (int)(pk >> 8), r = (int)(pk & 255u);
    sct[i] = tbl[a]; sst[i] = tbl[A_ + a]; srp[i] = tbl[2 * A_ + r];
  }
  if (tid < RG * 4) ((u64*)rowbits)[tid] = 0ull;
  __syncthreads();

  float mw  = mwp[0];
  float nmw = -mw;
  int   y   = yb * RG + row;
  float ycv = __fsub_rn((float)y, 127.5f);

  u64 pm[4] = {0ull, 0ull, 0ull, 0ull};

  for (int i = sub; i < cnt; i += SL) {
    float ct = sct[i], st = sst[i], rp = srp[i];
    float yst = __fmul_rn(ycv, st);
    bool neg = ct < 0.0f;                   // d decreasing in x -> flip coord
    int u1 = 0, u2 = 0;                     // first u with d>-mw / d>=mw
    #pragma unroll
    for (int s = 256; s; s >>= 1) {
      if (u1 + s <= 256) {
        int u = u1 + s - 1; int x = neg ? 255 - u : u;
        float d = __fsub_rn(__fadd_rn(__fmul_rn(__fsub_rn((float)x, 127.5f), ct), yst), rp);
        if (!(d > nmw)) u1 += s;
      }
      if (u2 + s <= 256) {
        int u = u2 + s - 1; int x = neg ? 255 - u : u;
        float d = __fsub_rn(__fadd_rn(__fmul_rn(__fsub_rn((float)x, 127.5f), ct), yst), rp);
        if (!(d >= mw)) u2 += s;
      }
    }
    if (u1 < u2) {                          // covered u in [u1,u2)
      int xlo = neg ? 256 - u2 : u1;
      int xhi = neg ? 255 - u1 : u2 - 1;
      #pragma unroll
      for (int w = 0; w < 4; ++w) {         // branchless word fold, static idx
        int lo = xlo - (w << 6); lo = lo < 0 ? 0 : lo;
        int hi = xhi - (w << 6); hi = hi > 63 ? 63 : hi;
        if (lo <= hi) pm[w] |= (~0ull >> (63 - hi)) & (~0ull << lo);
      }
    }
  }
  #pragma unroll
  for (int w = 0; w < 4; ++w)
    if (pm[w]) atomicOr(&rowbits[row][w], pm[w]);   // LDS atomic — no HBM
  __syncthreads();

  // bit -> float tile writeout, float4 coalesced; each pixel written once
  float* otile = out + (size_t)nc * 65536 + (size_t)yb * RG * 256;
  for (int j = tid; j < RG * 64; j += 256) {        // 64 float4 per row
    int rr = j >> 6, c4 = j & 63;
    u64 wbits = rowbits[rr][c4 >> 4];
    int sh = (c4 & 15) * 4;
    float4 v;
    v.x = (float)((wbits >> sh) & 1ull);
    v.y = (float)((wbits >> (sh + 1)) & 1ull);
    v.z = (float)((wbits >> (sh + 2)) & 1ull);
    v.w = (float)((wbits >> (sh + 3)) & 1ull);
    ((float4*)(otile + (size_t)rr * 256))[c4] = v;
  }
}

// ---------------------------------------------------------------------------
extern "C" void kernel_launch(void* const* d_in, const int* in_sizes, int n_in,
                              void* d_out, int out_size, void* d_ws, size_t ws_size,
                              hipStream_t stream) {
  const float* hm  = (const float*)d_in[0];   // [8,4,180,180] f32
  const float* mwp = (const float*)d_in[1];   // [1] f32
  const int*   Hp  = (const int*)d_in[2];     // [1] i32
  const int*   Wp  = (const int*)d_in[3];     // [1] i32
  float* out = (float*)d_out;                 // [8,4,256,256] f32

  char* base = (char*)d_ws;
  u32*  maxv = (u32*)(base + OFF_MAXV);
  u32*  cnt  = (u32*)(base + OFF_CNT);
  float* tbl = (float*)(base + OFF_TBL);
  u32*  list = (u32*)(base + OFF_LIST);

  // zero maxv + cnt (accumulated via atomics; deterministic per call)
  hipMemsetAsync(d_ws, 0, ZERO_BYTES, stream);

  maxtbl_kernel<<<dim3(9, NC), dim3(256), 0, stream>>>(hm, Hp, Wp, maxv, tbl);

  peaks_kernel<<<dim3((AR + 255) / 256, NC), dim3(256), 0, stream>>>(hm, maxv, cnt, list);

  raster_kernel<<<dim3(256 / RG, NC), dim3(256), 0, stream>>>(mwp, cnt, list, tbl, out);
}

// Round 6
// 49.675 us; speedup vs baseline: 1.7622x; 1.7622x over previous
//
#include <hip/hip_runtime.h>
#include <math.h>

// Problem dims (fixed by setup_inputs)
#define N_  8
#define C_  4
#define A_  180
#define R_  180
#define NC  (N_*C_)        // 32
#define AR  (A_*R_)        // 32400
#define CAP 1024           // max peaks per (n,c) — expected ~550, 20-sigma margin
#define ROWS_PB 8          // rows per raster block
#define SL  32             // peak slices per row

typedef unsigned long long u64;
typedef unsigned int u32;

// ws layout (bytes) — zeroed prefix = [0, OFF_TBL); total 530688 B (same as R2)
#define OFF_MAXV 0                       // u32 maxv[32] (encoded float keys)
#define OFF_CNT  128                     // u32 cnt[32*32] (one line per nc)
#define OFF_TBL  4224                    // float ct[180] st[180] rp[180] (2160 B)
#define OFF_PD   6400                    // float4 pdata[32][CAP] (512 KB), 16B-aligned
#define ZERO_BYTES OFF_TBL

// monotone float <-> u32 key (for atomicMax on possibly-negative floats)
// memset-0 init is below every valid key (fkey(finite) > 0)
__device__ __forceinline__ u32 fkey(float f) {
  u32 b = __float_as_uint(f);
  return (b & 0x80000000u) ? ~b : (b | 0x80000000u);
}
__device__ __forceinline__ float fval(u32 k) {
  u32 b = (k & 0x80000000u) ? (k ^ 0x80000000u) : ~k;
  return __uint_as_float(b);
}

// exact reference predicate value at u (u-space; ct2 = |ct|):
// for ct>0, u=x; for ct<0, u=255-x. Bit-exact vs reference since f32 RN is
// negation-symmetric and (x-127.5), (127.5-x) are exact halves.
__device__ __forceinline__ float probe_d(int u, float ct2, float yst, float rp) {
  return __fsub_rn(__fadd_rn(__fmul_rn(__fsub_rn((float)u, 127.5f), ct2), yst), rp);
}

// ---------------------------------------------------------------------------
// Kernel A: per-(n,c) max via 8 partial blocks + atomicMax (no return);
// block (8,0) builds trig/rho tables.
// ---------------------------------------------------------------------------
__global__ __launch_bounds__(256) void maxtbl_kernel(
    const float* __restrict__ hm,
    const int* __restrict__ Hp, const int* __restrict__ Wp,
    u32* __restrict__ maxv, float* __restrict__ tbl) {
  int bx = blockIdx.x, nc = blockIdx.y;
  if (bx < 8) {
    const float4* p = (const float4*)(hm + (size_t)nc * AR);  // 8100 float4
    float m = -INFINITY;
    for (int i = bx * 256 + threadIdx.x; i < AR / 4; i += 8 * 256) {
      float4 v = p[i];
      m = fmaxf(fmaxf(m, fmaxf(v.x, v.y)), fmaxf(v.z, v.w));
    }
    for (int off = 32; off; off >>= 1) m = fmaxf(m, __shfl_down(m, off, 64));
    __shared__ float sm[4];
    if ((threadIdx.x & 63) == 0) sm[threadIdx.x >> 6] = m;
    __syncthreads();
    if (threadIdx.x == 0) {
      m = fmaxf(fmaxf(sm[0], sm[1]), fmaxf(sm[2], sm[3]));
      atomicMax(&maxv[nc], fkey(m));
    }
  } else if (nc == 0) {
    int t = threadIdx.x;
    int H = Hp[0], W = Wp[0];
    double max_rho = sqrt((double)(W/2)*(double)(W/2) + (double)(H/2)*(double)(H/2));
    float drho = (float)(2.0 * max_rho / (double)(R_ - 1));
    if (t < A_) {
      // theta = f32(a) * f32(pi/A)  — matches jnp.arange(A,f32)*(np.pi/A)
      float theta = __fmul_rn((float)t, (float)(3.14159265358979323846 / (double)A_));
      tbl[t]        = (float)cos((double)theta);   // correctly-rounded f32
      tbl[A_ + t]   = (float)sin((double)theta);
      // r_phys = (f32(r) - 89.5) * f32(delta_rho)
      tbl[2*A_ + t] = __fmul_rn(__fsub_rn((float)t, (float)((R_-1)*0.5)), drho);
    }
  }
}

// ---------------------------------------------------------------------------
// Kernel B: peak detect -> compact EXPANDED list (ct, st, rp) as float4.
// ONE atomicAdd per wave (aggregated), counters padded one per 128-B line.
// peak := hm > 0.5*max AND no 3x3 neighbor strictly greater (== maxpool SAME)
// ---------------------------------------------------------------------------
__global__ __launch_bounds__(256) void peaks_kernel(
    const float* __restrict__ hm, const u32* __restrict__ maxv,
    const float* __restrict__ tbl,
    u32* __restrict__ cnt, float4* __restrict__ pdata) {
  int nc  = blockIdx.y;
  int idx = blockIdx.x * 256 + threadIdx.x;   // index within nc
  bool peak = false;
  int a = 0, r = 0;
  if (idx < AR) {
    const float* base = hm + (size_t)nc * AR;
    float val = base[idx];
    float thr = 0.5f * fval(maxv[nc]);
    if (val > thr) {
      a = idx / R_; r = idx - a * R_;
      peak = true;
      for (int da = -1; da <= 1 && peak; ++da) {
        int aa = a + da;
        if (aa < 0 || aa >= A_) continue;     // SAME pad with -inf
        for (int dr = -1; dr <= 1; ++dr) {
          if (da == 0 && dr == 0) continue;
          int rr = r + dr;
          if (rr < 0 || rr >= R_) continue;
          if (base[aa * R_ + rr] > val) { peak = false; break; }
        }
      }
    }
  }
  u64 m = __ballot(peak);
  if (m) {
    int lane = threadIdx.x & 63;
    int leader = (int)__ffsll((long long)m) - 1;
    u32 base_slot = 0;
    if (lane == leader) base_slot = atomicAdd(&cnt[nc * 32], (u32)__popcll(m));
    base_slot = (u32)__shfl((int)base_slot, leader, 64);
    if (peak) {
      u32 slot = base_slot + (u32)__popcll(m & ((1ull << lane) - 1ull));
      if (slot < CAP)
        pdata[(size_t)nc * CAP + slot] =
            make_float4(tbl[a], tbl[A_ + a], tbl[2 * A_ + r], 0.0f);
    }
  }
}

// ---------------------------------------------------------------------------
// Kernel C: raster. Block = (8-row stripe, nc); 256 thr = 8 rows x 32 slices.
// d(u) monotone non-decreasing in u (ct2>0, RN monotone) -> covered set is
// [u1,u2). Edges: division-guided. For ct2 >= 1e-3 the estimate error
// eps <= 8.4e-5/ct2 + 2e-4 < 0.09 << 0.5, so first-true index is in
// {ceil(q-0.5), +1}: ONE exact probe decides. Else (only a=90, |cos|~4e-8):
// full 9-probe lower_bound (s starts at 256 so the empty answer u=256 is
// reachable — R3 lesson). Per-row OR across 32 slices via shfl_xor tree
// (no LDS atomics), direct float4 tile writeout.
// ---------------------------------------------------------------------------
__global__ __launch_bounds__(256) void raster_kernel(
    const float* __restrict__ mwp,
    const u32* __restrict__ cntg, const float4* __restrict__ pdata,
    float* __restrict__ out) {
  __shared__ u64 rowbits[ROWS_PB][4];       // 256 B
  int yb  = blockIdx.x;                     // row stripe 0..31
  int nc  = blockIdx.y;
  int tid = threadIdx.x;
  int row = tid >> 5;                       // 0..7
  int sub = tid & (SL - 1);                 // 0..31

  int cnt = (int)cntg[nc * 32]; if (cnt > CAP) cnt = CAP;
  const float4* pdg = pdata + (size_t)nc * CAP;

  float mw  = mwp[0];
  float nmw = -mw;
  int   y   = yb * ROWS_PB + row;
  float ycv = __fsub_rn((float)y, 127.5f);

  u64 pm[4] = {0ull, 0ull, 0ull, 0ull};

  for (int i = sub; i < cnt; i += SL) {
    float4 pd = pdg[i];
    float ct = pd.x, st = pd.y, rp = pd.z;
    float ct2 = fabsf(ct);
    float yst = __fmul_rn(ycv, st);
    int u1, u2;
    if (ct2 >= 1e-3f) {
      // approx edges (rounding-mode-free math fine here; exactness comes
      // from the probes)
      float t   = rp - yst;
      float inv = __builtin_amdgcn_rcpf(ct2);          // 1-ulp v_rcp_f32
      float q1  = __fmaf_rn(t - mw, inv, 127.5f);
      float q2  = __fmaf_rn(t + mw, inv, 127.5f);
      q1 = fminf(fmaxf(q1, -2.0f), 260.0f);
      q2 = fminf(fmaxf(q2, -2.0f), 260.0f);
      int k1 = (int)ceilf(q1 - 0.5f); k1 = k1 < 0 ? 0 : (k1 > 255 ? 255 : k1);
      int k2 = (int)ceilf(q2 - 0.5f); k2 = k2 < 0 ? 0 : (k2 > 255 ? 255 : k2);
      float d1 = probe_d(k1, ct2, yst, rp);
      float d2 = probe_d(k2, ct2, yst, rp);
      u1 = k1 + ((d1 > nmw) ? 0 : 1);
      u2 = k2 + ((d2 >= mw) ? 0 : 1);
    } else {
      u1 = 0; u2 = 0;
      #pragma unroll
      for (int s = 256; s; s >>= 1) {
        if (u1 + s <= 256) {
          float d = probe_d(u1 + s - 1, ct2, yst, rp);
          if (!(d > nmw)) u1 += s;
        }
        if (u2 + s <= 256) {
          float d = probe_d(u2 + s - 1, ct2, yst, rp);
          if (!(d >= mw)) u2 += s;
        }
      }
    }
    if (u1 < u2) {                          // covered u in [u1,u2)
      bool neg = ct < 0.0f;                 // map back to x-space
      int xlo = neg ? 256 - u2 : u1;
      int xhi = neg ? 255 - u1 : u2 - 1;
      #pragma unroll
      for (int w = 0; w < 4; ++w) {         // branchless word fold, static idx
        int lo = xlo - (w << 6); lo = lo < 0 ? 0 : lo;
        int hi = xhi - (w << 6); hi = hi > 63 ? 63 : hi;
        if (lo <= hi) pm[w] |= (~0ull >> (63 - hi)) & (~0ull << lo);
      }
    }
  }

  // OR-reduce across the 32 slices of each row (lanes [0,32) / [32,64) are
  // distinct rows; xor masks < 32 stay within a row's lane group)
  #pragma unroll
  for (int m = 1; m < 32; m <<= 1) {
    pm[0] |= __shfl_xor(pm[0], m, 64);
    pm[1] |= __shfl_xor(pm[1], m, 64);
    pm[2] |= __shfl_xor(pm[2], m, 64);
    pm[3] |= __shfl_xor(pm[3], m, 64);
  }
  if (sub < 4) {                            // static-index select, no scratch
    u64 v = (sub == 0) ? pm[0] : (sub == 1) ? pm[1] : (sub == 2) ? pm[2] : pm[3];
    rowbits[row][sub] = v;                  // full overwrite — no zero-init
  }
  __syncthreads();

  // bit -> float tile writeout, float4 coalesced; each pixel written once
  float* otile = out + (size_t)nc * 65536 + (size_t)yb * ROWS_PB * 256;
  for (int j = tid; j < ROWS_PB * 64; j += 256) {   // 64 float4 per row
    int rr = j >> 6, c4 = j & 63;
    u64 wb = rowbits[rr][c4 >> 4];
    int sh = (c4 & 15) * 4;
    float4 v;
    v.x = (float)((wb >> sh) & 1ull);
    v.y = (float)((wb >> (sh + 1)) & 1ull);
    v.z = (float)((wb >> (sh + 2)) & 1ull);
    v.w = (float)((wb >> (sh + 3)) & 1ull);
    ((float4*)(otile + (size_t)rr * 256))[c4] = v;
  }
}

// ---------------------------------------------------------------------------
extern "C" void kernel_launch(void* const* d_in, const int* in_sizes, int n_in,
                              void* d_out, int out_size, void* d_ws, size_t ws_size,
                              hipStream_t stream) {
  const float* hm  = (const float*)d_in[0];   // [8,4,180,180] f32
  const float* mwp = (const float*)d_in[1];   // [1] f32
  const int*   Hp  = (const int*)d_in[2];     // [1] i32
  const int*   Wp  = (const int*)d_in[3];     // [1] i32
  float* out = (float*)d_out;                 // [8,4,256,256] f32

  char* base = (char*)d_ws;
  u32*   maxv  = (u32*)(base + OFF_MAXV);
  u32*   cnt   = (u32*)(base + OFF_CNT);
  float* tbl   = (float*)(base + OFF_TBL);
  float4* pdat = (float4*)(base + OFF_PD);

  // zero maxv + cnt (accumulated via atomics; deterministic per call)
  hipMemsetAsync(d_ws, 0, ZERO_BYTES, stream);

  maxtbl_kernel<<<dim3(9, NC), dim3(256), 0, stream>>>(hm, Hp, Wp, maxv, tbl);

  peaks_kernel<<<dim3((AR + 255) / 256, NC), dim3(256), 0, stream>>>(
      hm, maxv, tbl, cnt, pdat);

  raster_kernel<<<dim3(32, NC), dim3(256), 0, stream>>>(mwp, cnt, pdat, out);
}